// Round 7
// baseline (415.706 us; speedup 1.0000x reference)
//
#include <hip/hip_runtime.h>
#include <hip/hip_bf16.h>

#define NEG_SLOPE 0.2f

typedef short s16x8 __attribute__((ext_vector_type(8)));
typedef float f32x4 __attribute__((ext_vector_type(4)));

__device__ __forceinline__ unsigned short f2bf(float f) {
    unsigned int u = __float_as_uint(f);
    unsigned int r = (u + 0x7fffu + ((u >> 16) & 1u)) >> 16;
    return (unsigned short)r;
}
__device__ __forceinline__ float bf2f(unsigned int us) {
    return __uint_as_float(us << 16);
}

// ---------------- count + wl + W pre-split/transpose ----------------
// block0: wl1[k*8+h]=sum_d W1[k,h*64+d]*al1[h,d] (+4: ar1); wl2l/wl2r[k].
// block1: Wt1 hi/lo [n][k] bf16 planes (transposed W1).
// block2: Wt2 hi/lo [n][k].
// blocks 3..: edge count.

__global__ void count_wl_k(const int* __restrict__ dst, int* __restrict__ counts, int E,
                           const float* __restrict__ W1, const float* __restrict__ al1,
                           const float* __restrict__ ar1,
                           const float* __restrict__ W2, const float* __restrict__ al2,
                           const float* __restrict__ ar2,
                           float* __restrict__ wl1, float* __restrict__ wl2l,
                           float* __restrict__ wl2r,
                           unsigned int* __restrict__ wt1h, unsigned int* __restrict__ wt1l,
                           unsigned int* __restrict__ wt2h, unsigned int* __restrict__ wt2l) {
    const int bid = blockIdx.x;
    const int tid = threadIdx.x;
    if (bid == 0) {
        int k = tid;
        #pragma unroll
        for (int h = 0; h < 4; h++) {
            float sl = 0.f, sr = 0.f;
            #pragma unroll 8
            for (int d = 0; d < 64; d++) {
                float wv = W1[k * 256 + h * 64 + d];
                sl = fmaf(wv, al1[h * 64 + d], sl);
                sr = fmaf(wv, ar1[h * 64 + d], sr);
            }
            wl1[k * 8 + h] = sl;
            wl1[k * 8 + 4 + h] = sr;
        }
        float sl = 0.f, sr = 0.f;
        #pragma unroll 8
        for (int d = 0; d < 128; d++) {
            float wv = W2[k * 128 + d];
            sl = fmaf(wv, al2[d], sl);
            sr = fmaf(wv, ar2[d], sr);
        }
        wl2l[k] = sl;
        wl2r[k] = sr;
        return;
    }
    if (bid == 1) {   // Wt1[n][k] = W1[k][n], split
        int n = tid;
        for (int k = 0; k < 256; k += 2) {
            float v0 = W1[k * 256 + n], v1 = W1[(k + 1) * 256 + n];
            unsigned short h0 = f2bf(v0), h1 = f2bf(v1);
            unsigned short l0 = f2bf(v0 - bf2f(h0)), l1 = f2bf(v1 - bf2f(h1));
            wt1h[n * 128 + k / 2] = (unsigned int)h0 | ((unsigned int)h1 << 16);
            wt1l[n * 128 + k / 2] = (unsigned int)l0 | ((unsigned int)l1 << 16);
        }
        return;
    }
    if (bid == 2) {   // Wt2[n][k] = W2[k][n], split (n<128)
        int n = tid;
        if (n < 128) {
            for (int k = 0; k < 256; k += 2) {
                float v0 = W2[k * 128 + n], v1 = W2[(k + 1) * 128 + n];
                unsigned short h0 = f2bf(v0), h1 = f2bf(v1);
                unsigned short l0 = f2bf(v0 - bf2f(h0)), l1 = f2bf(v1 - bf2f(h1));
                wt2h[n * 128 + k / 2] = (unsigned int)h0 | ((unsigned int)h1 << 16);
                wt2l[n * 128 + k / 2] = (unsigned int)l0 | ((unsigned int)l1 << 16);
            }
        }
        return;
    }
    int e = (bid - 3) * 256 + tid;
    if (e < E) atomicAdd(&counts[dst[e]], 1);
}

// ---------------- single-dispatch scan (publish-then-wait lookback) ----------

__global__ __launch_bounds__(1024) void scan_k(const int* __restrict__ counts,
                                               int* __restrict__ flags,
                                               int* __restrict__ offsets,
                                               int* __restrict__ cursor, int n) {
    __shared__ int s_wt[16];
    __shared__ int s_base;
    const int tid = threadIdx.x, lane = tid & 63, wid = tid >> 6;
    const int bid = blockIdx.x;
    const int i = bid * 1024 + tid;
    int v = (i < n) ? counts[i] : 0;
    int incl = v;
    #pragma unroll
    for (int o = 1; o < 64; o <<= 1) {
        int t = __shfl_up(incl, o);
        if (lane >= o) incl += t;
    }
    if (lane == 63) s_wt[wid] = incl;
    __syncthreads();
    if (tid == 0) {
        int r = 0;
        #pragma unroll
        for (int w = 0; w < 16; w++) { int t = s_wt[w]; s_wt[w] = r; r += t; }
        atomicExch(&flags[bid], r + 1);   // publish block total
        s_base = 0;
    }
    __syncthreads();
    if (wid == 0) {
        int contrib = 0;
        if (lane < bid) {
            int f;
            while ((f = atomicAdd(&flags[lane], 0)) == 0) {}
            contrib = f - 1;
        }
        #pragma unroll
        for (int o = 32; o > 0; o >>= 1) contrib += __shfl_xor(contrib, o);
        if (lane == 0) s_base = contrib;
    }
    __syncthreads();
    if (i < n) {
        int excl = s_base + s_wt[wid] + (incl - v);
        offsets[i + 1] = excl + v;
        cursor[i] = excl;
    }
    if (bid == 0 && tid == 0) offsets[0] = 0;
}

__global__ void fill_csr_k(const int* __restrict__ src, const int* __restrict__ dst,
                           int* __restrict__ cursor, int* __restrict__ csr_src, int E) {
    int e = blockIdx.x * blockDim.x + threadIdx.x;
    if (e < E) {
        int pos = atomicAdd(&cursor[dst[e]], 1);
        csr_src[pos] = src[e];
    }
}

// ---------------- split feat -> bf16 hi/lo planes + el1/er1 ----------------
// 256 thr = 8 rows x 32 lanes, 8 channels/lane.

__global__ __launch_bounds__(256) void split1_k(const float* __restrict__ feat,
                                                const float* __restrict__ wl1,
                                                unsigned short* __restrict__ Ahi,
                                                unsigned short* __restrict__ Alo,
                                                float* __restrict__ el,
                                                float* __restrict__ er, int N) {
    __shared__ float s_wl[2048];
    const int tid = threadIdx.x;
    #pragma unroll
    for (int j = 0; j < 8; j++) s_wl[tid * 8 + j] = wl1[tid * 8 + j];
    __syncthreads();
    const int r = tid >> 5, c = tid & 31;
    const int row = blockIdx.x * 8 + r;
    if (row >= N) return;
    const int c0 = c * 8;
    float4 f0 = *(const float4*)&feat[(size_t)row * 256 + c0];
    float4 f1 = *(const float4*)&feat[(size_t)row * 256 + c0 + 4];
    float v[8] = {f0.x, f0.y, f0.z, f0.w, f1.x, f1.y, f1.z, f1.w};
    float pa[4] = {0.f, 0.f, 0.f, 0.f}, pb[4] = {0.f, 0.f, 0.f, 0.f};
    #pragma unroll
    for (int j = 0; j < 8; j++) {
        const float* wv = &s_wl[(c0 + j) * 8];
        #pragma unroll
        for (int h = 0; h < 4; h++) {
            pa[h] = fmaf(v[j], wv[h], pa[h]);
            pb[h] = fmaf(v[j], wv[4 + h], pb[h]);
        }
    }
    unsigned int hi[4], lo[4];
    #pragma unroll
    for (int j = 0; j < 4; j++) {
        unsigned short h0 = f2bf(v[2 * j]), h1 = f2bf(v[2 * j + 1]);
        unsigned short l0 = f2bf(v[2 * j] - bf2f(h0)), l1 = f2bf(v[2 * j + 1] - bf2f(h1));
        hi[j] = (unsigned int)h0 | ((unsigned int)h1 << 16);
        lo[j] = (unsigned int)l0 | ((unsigned int)l1 << 16);
    }
    *(uint4*)&Ahi[(size_t)row * 256 + c0] = uint4{hi[0], hi[1], hi[2], hi[3]};
    *(uint4*)&Alo[(size_t)row * 256 + c0] = uint4{lo[0], lo[1], lo[2], lo[3]};
    #pragma unroll
    for (int o = 1; o <= 16; o <<= 1) {
        #pragma unroll
        for (int h = 0; h < 4; h++) {
            pa[h] += __shfl_xor(pa[h], o);
            pb[h] += __shfl_xor(pb[h], o);
        }
    }
    if (c == 0) {
        *(float4*)&el[(size_t)row * 4] = float4{pa[0], pa[1], pa[2], pa[3]};
        *(float4*)&er[(size_t)row * 4] = float4{pb[0], pb[1], pb[2], pb[3]};
    }
}

// ---------------- pure bf16 3-term MFMA GEMM ----------------
// A planes [M][256] bf16, Bt planes [Nc][256] bf16 (pre-transposed W).
// Tile 128x64, 256 thr. XOR-swizzled unpadded LDS (uniform banks, 24 KB).
// Guard-free loads (OOB rows read into adjacent ws buffers; rows independent
// in MFMA so garbage stays in garbage rows; stores guarded).

__device__ __forceinline__ int sw(int row, int chunk) {   // short index, chunk=16B unit
    return row * 32 + ((chunk ^ (row & 3)) * 8);
}

__global__ __launch_bounds__(256) void gemm_k(const unsigned short* __restrict__ Ahi,
                                              const unsigned short* __restrict__ Alo,
                                              const unsigned short* __restrict__ Bth,
                                              const unsigned short* __restrict__ Btl,
                                              unsigned short* __restrict__ Cb,
                                              int M, int Nc) {
    __shared__ __align__(16) unsigned short As_hi[128 * 32], As_lo[128 * 32];
    __shared__ __align__(16) unsigned short Bs_hi[64 * 32],  Bs_lo[64 * 32];

    const int tid = threadIdx.x;
    const int lane = tid & 63, wid = tid >> 6;
    const int by = blockIdx.x;              // column block (fastest: A-tile L2 reuse)
    const int row0 = blockIdx.y * 128;
    const int col0 = by * 64;
    const int wm = (wid & 1) * 64;
    const int wn = (wid >> 1) * 32;
    const int quad = lane >> 4, mrow = lane & 15;

    const int row_a = tid >> 1, ca = tid & 1;     // A: 2 chunks (ca, ca+2) per thread
    const int row_b = tid >> 2, cb = tid & 3;     // B: 1 chunk per thread
    const size_t abase = (size_t)(row0 + row_a) * 256 + ca * 8;
    const size_t bbase = (size_t)(col0 + row_b) * 256 + cb * 8;

    f32x4 acc[4][2];
    #pragma unroll
    for (int i = 0; i < 4; i++)
        #pragma unroll
        for (int j = 0; j < 2; j++) acc[i][j] = f32x4{0.f, 0.f, 0.f, 0.f};

    uint4 rah0, rah1, ral0, ral1, rbh, rbl;
    rah0 = *(const uint4*)&Ahi[abase];
    rah1 = *(const uint4*)&Ahi[abase + 16];
    ral0 = *(const uint4*)&Alo[abase];
    ral1 = *(const uint4*)&Alo[abase + 16];
    rbh  = *(const uint4*)&Bth[bbase];
    rbl  = *(const uint4*)&Btl[bbase];

    for (int k0 = 0; k0 < 256; k0 += 32) {
        *(uint4*)&As_hi[sw(row_a, ca)]     = rah0;
        *(uint4*)&As_hi[sw(row_a, ca + 2)] = rah1;
        *(uint4*)&As_lo[sw(row_a, ca)]     = ral0;
        *(uint4*)&As_lo[sw(row_a, ca + 2)] = ral1;
        *(uint4*)&Bs_hi[sw(row_b, cb)]     = rbh;
        *(uint4*)&Bs_lo[sw(row_b, cb)]     = rbl;
        __syncthreads();
        if (k0 < 224) {
            rah0 = *(const uint4*)&Ahi[abase + k0 + 32];
            rah1 = *(const uint4*)&Ahi[abase + k0 + 48];
            ral0 = *(const uint4*)&Alo[abase + k0 + 32];
            ral1 = *(const uint4*)&Alo[abase + k0 + 48];
            rbh  = *(const uint4*)&Bth[bbase + k0 + 32];
            rbl  = *(const uint4*)&Btl[bbase + k0 + 32];
        }
        s16x8 ah[4], al4[4], bh[2], bl[2];
        #pragma unroll
        for (int i = 0; i < 4; i++) {
            int r = wm + 16 * i + mrow;
            ah[i]  = *(const s16x8*)&As_hi[sw(r, quad)];
            al4[i] = *(const s16x8*)&As_lo[sw(r, quad)];
        }
        #pragma unroll
        for (int j = 0; j < 2; j++) {
            int r = wn + 16 * j + mrow;
            bh[j] = *(const s16x8*)&Bs_hi[sw(r, quad)];
            bl[j] = *(const s16x8*)&Bs_lo[sw(r, quad)];
        }
        #pragma unroll
        for (int i = 0; i < 4; i++)
            #pragma unroll
            for (int j = 0; j < 2; j++) {
                acc[i][j] = __builtin_amdgcn_mfma_f32_16x16x32_bf16(ah[i],  bh[j], acc[i][j], 0, 0, 0);
                acc[i][j] = __builtin_amdgcn_mfma_f32_16x16x32_bf16(ah[i],  bl[j], acc[i][j], 0, 0, 0);
                acc[i][j] = __builtin_amdgcn_mfma_f32_16x16x32_bf16(al4[i], bh[j], acc[i][j], 0, 0, 0);
            }
        __syncthreads();
    }

    #pragma unroll
    for (int i = 0; i < 4; i++) {
        #pragma unroll
        for (int j = 0; j < 2; j++) {
            int col = col0 + wn + 16 * j + mrow;
            int rbase = row0 + wm + 16 * i + quad * 4;
            #pragma unroll
            for (int r = 0; r < 4; r++) {
                int row = rbase + r;
                if (row < M) Cb[(size_t)row * Nc + col] = f2bf(acc[i][j][r]);
            }
        }
    }
}

// ---------------- fused edge-softmax + wide-row gather-aggregate ----------------

__device__ __forceinline__ void fma8(float* acc, float wgt, uint4 u) {
    acc[0] = fmaf(wgt, bf2f(u.x & 0xffff), acc[0]);
    acc[1] = fmaf(wgt, bf2f(u.x >> 16),    acc[1]);
    acc[2] = fmaf(wgt, bf2f(u.y & 0xffff), acc[2]);
    acc[3] = fmaf(wgt, bf2f(u.y >> 16),    acc[3]);
    acc[4] = fmaf(wgt, bf2f(u.z & 0xffff), acc[4]);
    acc[5] = fmaf(wgt, bf2f(u.z >> 16),    acc[5]);
    acc[6] = fmaf(wgt, bf2f(u.w & 0xffff), acc[6]);
    acc[7] = fmaf(wgt, bf2f(u.w >> 16),    acc[7]);
}

// WP=true (layer1): epilogue writes h1 hi/lo bf16 planes + el2/er2 (fp32 path).
// WP=false (layer2): epilogue writes fp32 out.
template <int H, int D, bool RELU, bool WP>
__global__ __launch_bounds__(256) void fagg_k(const unsigned short* __restrict__ ft,
                                              const float* __restrict__ el,
                                              const float* __restrict__ er,
                                              const int* __restrict__ offsets,
                                              const int* __restrict__ csr_src,
                                              const float* __restrict__ bias,
                                              float* __restrict__ out, int n_nodes,
                                              const float* __restrict__ wl2l,
                                              const float* __restrict__ wl2r,
                                              unsigned short* __restrict__ phi,
                                              unsigned short* __restrict__ plo,
                                              float* __restrict__ el2,
                                              float* __restrict__ er2) {
    constexpr int HD = H * D;
    constexpr int LPE = HD / 8;    // lanes per edge-row (16B/lane): 32 (L1), 16 (L2)
    constexpr int EPI = 64 / LPE;  // edges per wave-load: 2 (L1), 4 (L2)
    const int lane = threadIdx.x & 63;
    const int w = threadIdx.x >> 6;
    const int n = blockIdx.x * 4 + w;
    __shared__ int   s_src[4][64];
    __shared__ float s_a[4][64 * H];
    if (n >= n_nodes) return;
    const int off = offsets[n];
    const int deg = offsets[n + 1] - off;
    const int lane_sub = lane & (LPE - 1);
    const int q = lane / LPE;
    const int c0 = lane_sub * 8;
    const int h_of = c0 / D;

    float ern[H];
    #pragma unroll
    for (int h = 0; h < H; h++) ern[h] = er[n * H + h];

    float acc[8];
    #pragma unroll
    for (int t = 0; t < 8; t++) acc[t] = 0.f;

    const int* s_src_w = s_src[w];
    const float* s_a_w = s_a[w];
    const uint4* fp = ((const uint4*)ft) + lane_sub;

    if (deg <= 64) {
        const bool act = lane < deg;
        int sv = act ? csr_src[off + lane] : 0;
        s_src[w][lane] = sv;
        float evr[H];
        if constexpr (H == 4) {
            float4 e4 = ((const float4*)el)[sv];
            evr[0] = e4.x; evr[1] = e4.y; evr[2] = e4.z; evr[3] = e4.w;
        } else {
            evr[0] = el[sv];
        }
        int p0 = s_src_w[q], p1 = s_src_w[EPI + q];
        int p2 = s_src_w[2 * EPI + q], p3 = s_src_w[3 * EPI + q];
        uint4 u0 = fp[(size_t)p0 * LPE];
        uint4 u1 = fp[(size_t)p1 * LPE];
        uint4 u2 = fp[(size_t)p2 * LPE];
        uint4 u3 = fp[(size_t)p3 * LPE];
        float ev[H], m[H];
        #pragma unroll
        for (int h = 0; h < H; h++) {
            float t = evr[h] + ern[h];
            t = t > 0.f ? t : NEG_SLOPE * t;
            ev[h] = act ? t : -1e30f;
            m[h] = ev[h];
        }
        #pragma unroll
        for (int h = 0; h < H; h++)
            for (int o = 32; o > 0; o >>= 1) m[h] = fmaxf(m[h], __shfl_xor(m[h], o));
        float ex[H], sm[H];
        #pragma unroll
        for (int h = 0; h < H; h++) { ex[h] = act ? __expf(ev[h] - m[h]) : 0.f; sm[h] = ex[h]; }
        #pragma unroll
        for (int h = 0; h < H; h++)
            for (int o = 32; o > 0; o >>= 1) sm[h] += __shfl_xor(sm[h], o);
        #pragma unroll
        for (int h = 0; h < H; h++)
            s_a[w][lane * H + h] = ex[h] * (sm[h] > 0.f ? 1.f / sm[h] : 0.f);
        fma8(acc, s_a_w[(q) * H + h_of], u0);
        fma8(acc, s_a_w[(EPI + q) * H + h_of], u1);
        fma8(acc, s_a_w[(2 * EPI + q) * H + h_of], u2);
        fma8(acc, s_a_w[(3 * EPI + q) * H + h_of], u3);
        const int rc = (deg + EPI - 1) & ~(EPI - 1);
        int i = 4 * EPI;
        for (; i + 4 * EPI <= rc; i += 4 * EPI) {
            int e0 = i + q, e1 = i + EPI + q, e2 = i + 2 * EPI + q, e3 = i + 3 * EPI + q;
            int s0 = s_src_w[e0], s1 = s_src_w[e1], s2 = s_src_w[e2], s3 = s_src_w[e3];
            uint4 v0 = fp[(size_t)s0 * LPE];
            uint4 v1 = fp[(size_t)s1 * LPE];
            uint4 v2 = fp[(size_t)s2 * LPE];
            uint4 v3 = fp[(size_t)s3 * LPE];
            float w0 = s_a_w[e0 * H + h_of], w1 = s_a_w[e1 * H + h_of];
            float w2 = s_a_w[e2 * H + h_of], w3 = s_a_w[e3 * H + h_of];
            fma8(acc, w0, v0); fma8(acc, w1, v1); fma8(acc, w2, v2); fma8(acc, w3, v3);
        }
        for (; i < rc; i += EPI) {
            int e = i + q;
            int s = s_src_w[e];
            uint4 v = fp[(size_t)s * LPE];
            fma8(acc, s_a_w[e * H + h_of], v);
        }
    } else {
        // ---- rare slow path ----
        float m[H];
        #pragma unroll
        for (int h = 0; h < H; h++) m[h] = -1e30f;
        for (int i = lane; i < deg; i += 64) {
            int sv = csr_src[off + i];
            if constexpr (H == 4) {
                float4 e4 = ((const float4*)el)[sv];
                float tmp[4] = {e4.x, e4.y, e4.z, e4.w};
                #pragma unroll
                for (int h = 0; h < 4; h++) {
                    float t = tmp[h] + ern[h];
                    t = t > 0.f ? t : NEG_SLOPE * t;
                    m[h] = fmaxf(m[h], t);
                }
            } else {
                float t = el[sv] + ern[0];
                t = t > 0.f ? t : NEG_SLOPE * t;
                m[0] = fmaxf(m[0], t);
            }
        }
        #pragma unroll
        for (int h = 0; h < H; h++)
            for (int o = 32; o > 0; o >>= 1) m[h] = fmaxf(m[h], __shfl_xor(m[h], o));
        float sm[H];
        #pragma unroll
        for (int h = 0; h < H; h++) sm[h] = 0.f;
        for (int i = lane; i < deg; i += 64) {
            int sv = csr_src[off + i];
            if constexpr (H == 4) {
                float4 e4 = ((const float4*)el)[sv];
                float tmp[4] = {e4.x, e4.y, e4.z, e4.w};
                #pragma unroll
                for (int h = 0; h < 4; h++) {
                    float t = tmp[h] + ern[h];
                    t = t > 0.f ? t : NEG_SLOPE * t;
                    sm[h] += __expf(t - m[h]);
                }
            } else {
                float t = el[sv] + ern[0];
                t = t > 0.f ? t : NEG_SLOPE * t;
                sm[0] += __expf(t - m[0]);
            }
        }
        #pragma unroll
        for (int h = 0; h < H; h++)
            for (int o = 32; o > 0; o >>= 1) sm[h] += __shfl_xor(sm[h], o);
        float inv[H];
        #pragma unroll
        for (int h = 0; h < H; h++) inv[h] = (sm[h] > 0.f) ? (1.f / sm[h]) : 0.f;
        for (int base = 0; base < deg; base += 64) {
            const bool act2 = base + lane < deg;
            int sv = act2 ? csr_src[off + base + lane] : 0;
            s_src[w][lane] = sv;
            float exh[H];
            if constexpr (H == 4) {
                float4 e4 = ((const float4*)el)[sv];
                float tmp[4] = {e4.x, e4.y, e4.z, e4.w};
                #pragma unroll
                for (int h = 0; h < 4; h++) {
                    float t = tmp[h] + ern[h];
                    t = t > 0.f ? t : NEG_SLOPE * t;
                    exh[h] = act2 ? __expf(t - m[h]) * inv[h] : 0.f;
                }
            } else {
                float t = el[sv] + ern[0];
                t = t > 0.f ? t : NEG_SLOPE * t;
                exh[0] = act2 ? __expf(t - m[0]) * inv[0] : 0.f;
            }
            #pragma unroll
            for (int h = 0; h < H; h++) s_a[w][lane * H + h] = exh[h];
            int cnt = min(64, deg - base);
            int rc = (cnt + EPI - 1) & ~(EPI - 1);
            int i = 0;
            for (; i + 4 * EPI <= rc; i += 4 * EPI) {
                int e0 = i + q, e1 = i + EPI + q, e2 = i + 2 * EPI + q, e3 = i + 3 * EPI + q;
                int s0 = s_src_w[e0], s1 = s_src_w[e1], s2 = s_src_w[e2], s3 = s_src_w[e3];
                uint4 v0 = fp[(size_t)s0 * LPE];
                uint4 v1 = fp[(size_t)s1 * LPE];
                uint4 v2 = fp[(size_t)s2 * LPE];
                uint4 v3 = fp[(size_t)s3 * LPE];
                float w0 = s_a_w[e0 * H + h_of], w1 = s_a_w[e1 * H + h_of];
                float w2 = s_a_w[e2 * H + h_of], w3 = s_a_w[e3 * H + h_of];
                fma8(acc, w0, v0); fma8(acc, w1, v1); fma8(acc, w2, v2); fma8(acc, w3, v3);
            }
            for (; i < rc; i += EPI) {
                int e = i + q;
                int s = s_src_w[e];
                uint4 v = fp[(size_t)s * LPE];
                fma8(acc, s_a_w[e * H + h_of], v);
            }
        }
    }

    // fold edge sub-groups (all lanes end with full sums)
    #pragma unroll
    for (int t = 0; t < 8; t++) {
        #pragma unroll
        for (int s = LPE; s < 64; s <<= 1) acc[t] += __shfl_xor(acc[t], s);
    }

    if constexpr (WP) {
        // layer1: bias+relu, write h1 hi/lo planes, compute el2/er2
        const int ls = lane & 31;
        float4 b0 = ((const float4*)bias)[ls * 2];
        float4 b1 = ((const float4*)bias)[ls * 2 + 1];
        float v[8] = {acc[0] + b0.x, acc[1] + b0.y, acc[2] + b0.z, acc[3] + b0.w,
                      acc[4] + b1.x, acc[5] + b1.y, acc[6] + b1.z, acc[7] + b1.w};
        #pragma unroll
        for (int t = 0; t < 8; t++) v[t] = fmaxf(v[t], 0.f);
        if (lane < 32) {
            uint4 hp, lp;
            unsigned short h0, h1;
            h0 = f2bf(v[0]); h1 = f2bf(v[1]);
            hp.x = (unsigned int)h0 | ((unsigned int)h1 << 16);
            lp.x = (unsigned int)f2bf(v[0] - bf2f(h0)) | ((unsigned int)f2bf(v[1] - bf2f(h1)) << 16);
            h0 = f2bf(v[2]); h1 = f2bf(v[3]);
            hp.y = (unsigned int)h0 | ((unsigned int)h1 << 16);
            lp.y = (unsigned int)f2bf(v[2] - bf2f(h0)) | ((unsigned int)f2bf(v[3] - bf2f(h1)) << 16);
            h0 = f2bf(v[4]); h1 = f2bf(v[5]);
            hp.z = (unsigned int)h0 | ((unsigned int)h1 << 16);
            lp.z = (unsigned int)f2bf(v[4] - bf2f(h0)) | ((unsigned int)f2bf(v[5] - bf2f(h1)) << 16);
            h0 = f2bf(v[6]); h1 = f2bf(v[7]);
            hp.w = (unsigned int)h0 | ((unsigned int)h1 << 16);
            lp.w = (unsigned int)f2bf(v[6] - bf2f(h0)) | ((unsigned int)f2bf(v[7] - bf2f(h1)) << 16);
            ((uint4*)phi)[(size_t)n * 32 + ls] = hp;
            ((uint4*)plo)[(size_t)n * 32 + ls] = lp;
        }
        float4 wa0 = ((const float4*)wl2l)[ls * 2], wa1 = ((const float4*)wl2l)[ls * 2 + 1];
        float4 wb0 = ((const float4*)wl2r)[ls * 2], wb1 = ((const float4*)wl2r)[ls * 2 + 1];
        float pe = v[0] * wa0.x + v[1] * wa0.y + v[2] * wa0.z + v[3] * wa0.w +
                   v[4] * wa1.x + v[5] * wa1.y + v[6] * wa1.z + v[7] * wa1.w;
        float pr = v[0] * wb0.x + v[1] * wb0.y + v[2] * wb0.z + v[3] * wb0.w +
                   v[4] * wb1.x + v[5] * wb1.y + v[6] * wb1.z + v[7] * wb1.w;
        #pragma unroll
        for (int o = 1; o <= 16; o <<= 1) { pe += __shfl_xor(pe, o); pr += __shfl_xor(pr, o); }
        if (lane == 0) { el2[n] = pe; er2[n] = pr; }
    } else {
        if (lane < LPE) {
            float4 b0 = ((const float4*)bias)[lane * 2];
            float4 b1 = ((const float4*)bias)[lane * 2 + 1];
            float4 o0{acc[0] + b0.x, acc[1] + b0.y, acc[2] + b0.z, acc[3] + b0.w};
            float4 o1{acc[4] + b1.x, acc[5] + b1.y, acc[6] + b1.z, acc[7] + b1.w};
            if (RELU) {
                o0.x = fmaxf(o0.x, 0.f); o0.y = fmaxf(o0.y, 0.f);
                o0.z = fmaxf(o0.z, 0.f); o0.w = fmaxf(o0.w, 0.f);
                o1.x = fmaxf(o1.x, 0.f); o1.y = fmaxf(o1.y, 0.f);
                o1.z = fmaxf(o1.z, 0.f); o1.w = fmaxf(o1.w, 0.f);
            }
            float4* op = (float4*)out + (size_t)n * (HD / 4) + lane * 2;
            op[0] = o0;
            op[1] = o1;
        }
    }
}

// ---------------- launch ----------------

extern "C" void kernel_launch(void* const* d_in, const int* in_sizes, int n_in,
                              void* d_out, int out_size, void* d_ws, size_t ws_size,
                              hipStream_t stream) {
    const float* feat    = (const float*)d_in[0];
    const int*   src     = (const int*)d_in[1];
    const int*   dst     = (const int*)d_in[2];
    const float* W1      = (const float*)d_in[3];
    const float* attn_l1 = (const float*)d_in[4];
    const float* attn_r1 = (const float*)d_in[5];
    const float* bias1   = (const float*)d_in[6];
    const float* W2      = (const float*)d_in[7];
    const float* attn_l2 = (const float*)d_in[8];
    const float* attn_r2 = (const float*)d_in[9];
    const float* bias2   = (const float*)d_in[10];
    float* out = (float*)d_out;

    const int N = in_sizes[0] / 256;   // 50000
    const int E = in_sizes[1];         // 800000
    const int NB = (N + 1023) / 1024;  // 49 (<= 64 for lookback wave)

    char* ws = (char*)d_ws;
    size_t o = 0;
    auto alloc = [&](size_t bytes) -> void* {
        void* p = ws + o;
        o = (o + bytes + 255) & ~(size_t)255;
        return p;
    };
    int* counts  = (int*)alloc((size_t)(N + 64) * 4);
    int* flags   = counts + N;
    int* cursor  = (int*)alloc((size_t)N * 4);
    int* offsets = (int*)alloc((size_t)(N + 1) * 4);
    int* csr_src = (int*)alloc((size_t)E * 4);
    // A1 planes; h1 planes ALIAS them (A1 dead after gemm1, h1 written by fagg1)
    unsigned short* A1hi = (unsigned short*)alloc((size_t)N * 256 * 2);
    unsigned short* A1lo = (unsigned short*)alloc((size_t)N * 256 * 2);
    unsigned short* h1hi = A1hi;
    unsigned short* h1lo = A1lo;
    unsigned short* ft1b = (unsigned short*)alloc((size_t)N * 256 * 2);  // gemm C (both layers)
    unsigned short* ft2b = ft1b;
    unsigned int* wt1h = (unsigned int*)alloc(256 * 128 * 4);
    unsigned int* wt1l = (unsigned int*)alloc(256 * 128 * 4);
    unsigned int* wt2h = (unsigned int*)alloc(128 * 128 * 4);
    unsigned int* wt2l = (unsigned int*)alloc(128 * 128 * 4);
    float* wl1  = (float*)alloc(256 * 8 * 4);
    float* wl2l = (float*)alloc(256 * 4);
    float* wl2r = (float*)alloc(256 * 4);
    float* el1 = (float*)alloc((size_t)N * 4 * 4);
    float* er1 = (float*)alloc((size_t)N * 4 * 4);
    float* el2 = (float*)alloc((size_t)N * 4);
    float* er2 = (float*)alloc((size_t)N * 4);

    hipMemsetAsync(counts, 0, (size_t)(N + 64) * 4, stream);
    count_wl_k<<<3 + (E + 255) / 256, 256, 0, stream>>>(dst, counts, E,
        W1, attn_l1, attn_r1, W2, attn_l2, attn_r2,
        wl1, wl2l, wl2r, wt1h, wt1l, wt2h, wt2l);
    scan_k<<<NB, 1024, 0, stream>>>(counts, flags, offsets, cursor, N);
    fill_csr_k<<<(E + 255) / 256, 256, 0, stream>>>(src, dst, cursor, csr_src, E);
    split1_k<<<(N + 7) / 8, 256, 0, stream>>>(feat, wl1, A1hi, A1lo, el1, er1, N);

    // layer 1
    gemm_k<<<dim3(4, (N + 127) / 128), 256, 0, stream>>>(A1hi, A1lo,
        (const unsigned short*)wt1h, (const unsigned short*)wt1l, ft1b, N, 256);
    fagg_k<4, 64, true, true><<<(N + 3) / 4, 256, 0, stream>>>(ft1b, el1, er1, offsets,
        csr_src, bias1, nullptr, N, wl2l, wl2r, h1hi, h1lo, el2, er2);

    // layer 2
    gemm_k<<<dim3(2, (N + 127) / 128), 256, 0, stream>>>(h1hi, h1lo,
        (const unsigned short*)wt2h, (const unsigned short*)wt2l, ft2b, N, 128);
    fagg_k<1, 128, false, false><<<(N + 3) / 4, 256, 0, stream>>>(ft2b, el2, er2, offsets,
        csr_src, bias2, out, N, nullptr, nullptr, nullptr, nullptr, nullptr, nullptr);
}